// Round 2
// baseline (411.684 us; speedup 1.0000x reference)
//
#include <hip/hip_runtime.h>

#define FDIM 128
#define HEADS 4
#define CD 32

// K1: xw[N,128] = x[N,128] @ W[128,128]  (f32)
__global__ __launch_bounds__(256) void k_gemm(const float* __restrict__ x,
                                              const float* __restrict__ w,
                                              float* __restrict__ xw, int N)
{
    __shared__ float Wl[FDIM * FDIM];   // 64 KB
    __shared__ float xs[32 * FDIM];     // 16 KB
    int t = threadIdx.x;
    int row0 = blockIdx.x * 32;
    // stage W (4096 float4)
    for (int i = t; i < FDIM * FDIM / 4; i += 256)
        ((float4*)Wl)[i] = ((const float4*)w)[i];
    // stage x tile (1024 float4, 32 float4 per row)
    for (int i = t; i < 32 * FDIM / 4; i += 256) {
        int r = row0 + (i >> 5);
        float4 v = make_float4(0.f, 0.f, 0.f, 0.f);
        if (r < N) v = ((const float4*)x)[(size_t)row0 * 32 + i];
        ((float4*)xs)[i] = v;
    }
    __syncthreads();
    int c = t & 127;     // output column
    int rg = t >> 7;     // row group 0..1 (16 rows each)
    float acc[16];
#pragma unroll
    for (int i = 0; i < 16; i++) acc[i] = 0.f;
    for (int k = 0; k < FDIM; k++) {
        float wv = Wl[k * FDIM + c];
        const float* xp = &xs[(rg * 16) * FDIM + k];
#pragma unroll
        for (int i = 0; i < 16; i++) acc[i] += xp[i * FDIM] * wv;
    }
#pragma unroll
    for (int i = 0; i < 16; i++) {
        int r = row0 + rg * 16 + i;
        if (r < N) xw[(size_t)r * FDIM + c] = acc[i];
    }
}

// K2: per-node attention half-logits a_src[n,h], a_dst[n,h]
__global__ __launch_bounds__(256) void k_logits(const float* __restrict__ xw,
                                                const float* __restrict__ att,
                                                float* __restrict__ a_src,
                                                float* __restrict__ a_dst, int N)
{
    __shared__ float attl[HEADS * 2 * CD];  // 256 floats
    int t = threadIdx.x;
    attl[t] = att[t];
    __syncthreads();
    int gid = blockIdx.x * 256 + t;
    if (gid >= N * HEADS) return;
    int n = gid >> 2, h = gid & 3;
    const float* xp = &xw[(size_t)n * FDIM + h * CD];
    const float* as = &attl[h * 2 * CD];
    const float* ad = as + CD;
    float s = 0.f, d = 0.f;
#pragma unroll
    for (int ci = 0; ci < CD; ci++) { float v = xp[ci]; s += v * as[ci]; d += v * ad[ci]; }
    a_src[gid] = s;
    a_dst[gid] = d;
}

// K3: zero accumulators (out_acc N*32, seg N*4)
__global__ void k_init(float* __restrict__ out_acc, float* __restrict__ seg, int N)
{
    int i = blockIdx.x * 256 + threadIdx.x;
    if (i < N * CD) out_acc[i] = 0.f;
    if (i < N * HEADS) seg[i] = 0.f;
}

// K4: softmax denominators: seg[row,h] += exp(leaky(a_src[row,h]+a_dst[col,h]))
__global__ __launch_bounds__(256) void k_esum(const int* __restrict__ ei, int E,
                                              const float* __restrict__ a_src,
                                              const float* __restrict__ a_dst,
                                              float* __restrict__ seg)
{
    int e = blockIdx.x * 256 + threadIdx.x;
    if (e >= E) return;
    int r = ei[e], cl = ei[E + e];
    const float4 as = *(const float4*)&a_src[r * 4];
    const float4 ad = *(const float4*)&a_dst[cl * 4];
    float a[4] = {as.x + ad.x, as.y + ad.y, as.z + ad.z, as.w + ad.w};
#pragma unroll
    for (int h = 0; h < 4; h++) {
        float v = a[h] >= 0.f ? a[h] : 0.2f * a[h];
        atomicAdd(&seg[r * 4 + h], __expf(v));
    }
}

// K5: scatter messages: out_acc[col,c] += (1/H) * sum_h alpha[e,h]*xw[row,h,c]
// 32 lanes per edge (one per channel), 8 edges per block
__global__ __launch_bounds__(256) void k_scatter(const int* __restrict__ ei, int E,
                                                 const float* __restrict__ a_src,
                                                 const float* __restrict__ a_dst,
                                                 const float* __restrict__ seg,
                                                 const float* __restrict__ xw,
                                                 float* __restrict__ out_acc)
{
    int t = threadIdx.x;
    int le = t >> 5, c = t & 31;
    int e = blockIdx.x * 8 + le;
    if (e >= E) return;
    int r = ei[e], cl = ei[E + e];
    int lane = t & 63;
    float av = 0.f;
    if (c < 4) {
        float a = a_src[r * 4 + c] + a_dst[cl * 4 + c];
        a = a >= 0.f ? a : 0.2f * a;
        av = __expf(a) / (seg[r * 4 + c] + 1e-16f);
    }
    float v = 0.f;
#pragma unroll
    for (int h = 0; h < 4; h++) {
        float ah = __shfl(av, (lane & 32) + h, 64);
        v += ah * xw[(size_t)r * FDIM + h * CD + c];
    }
    atomicAdd(&out_acc[cl * CD + c], 0.25f * v);
}

// K6: out = out_acc + bias  (f32)
__global__ void k_final(const float* __restrict__ out_acc, const float* __restrict__ bias,
                        float* __restrict__ out, int N)
{
    int i = blockIdx.x * 256 + threadIdx.x;
    if (i >= N * CD) return;
    out[i] = out_acc[i] + bias[i & 31];
}

extern "C" void kernel_launch(void* const* d_in, const int* in_sizes, int n_in,
                              void* d_out, int out_size, void* d_ws, size_t ws_size,
                              hipStream_t stream)
{
    const float* x    = (const float*)d_in[0];
    const int*   ei   = (const int*)d_in[1];
    const float* w    = (const float*)d_in[2];
    const float* att  = (const float*)d_in[3];
    const float* bias = (const float*)d_in[4];
    float* out = (float*)d_out;
    int N = in_sizes[0] / FDIM;
    int E = in_sizes[1] / 2;

    float* ws      = (float*)d_ws;
    float* xw      = ws;                           // N*128
    float* a_src   = xw + (size_t)N * FDIM;        // N*4
    float* a_dst   = a_src + (size_t)N * HEADS;    // N*4
    float* seg     = a_dst + (size_t)N * HEADS;    // N*4
    float* out_acc = seg + (size_t)N * HEADS;      // N*32

    k_gemm<<<(N + 31) / 32, 256, 0, stream>>>(x, w, xw, N);
    k_logits<<<(N * HEADS + 255) / 256, 256, 0, stream>>>(xw, att, a_src, a_dst, N);
    k_init<<<(N * CD + 255) / 256, 256, 0, stream>>>(out_acc, seg, N);
    k_esum<<<(E + 255) / 256, 256, 0, stream>>>(ei, E, a_src, a_dst, seg);
    k_scatter<<<(E + 7) / 8, 256, 0, stream>>>(ei, E, a_src, a_dst, seg, xw, out_acc);
    k_final<<<(N * CD + 255) / 256, 256, 0, stream>>>(out_acc, bias, out, N);
}

// Round 3
// 288.440 us; speedup vs baseline: 1.4273x; 1.4273x over previous
//
#include <hip/hip_runtime.h>

#define FDIM 128
#define HEADS 4
#define CD 32

// K1: xw[N,128] = x[N,128] @ W[128,128]  (f32)
__global__ __launch_bounds__(256) void k_gemm(const float* __restrict__ x,
                                              const float* __restrict__ w,
                                              float* __restrict__ xw, int N)
{
    __shared__ float Wl[FDIM * FDIM];   // 64 KB
    __shared__ float xs[32 * FDIM];     // 16 KB
    int t = threadIdx.x;
    int row0 = blockIdx.x * 32;
    for (int i = t; i < FDIM * FDIM / 4; i += 256)
        ((float4*)Wl)[i] = ((const float4*)w)[i];
    for (int i = t; i < 32 * FDIM / 4; i += 256) {
        int r = row0 + (i >> 5);
        float4 v = make_float4(0.f, 0.f, 0.f, 0.f);
        if (r < N) v = ((const float4*)x)[(size_t)row0 * 32 + i];
        ((float4*)xs)[i] = v;
    }
    __syncthreads();
    int c = t & 127;
    int rg = t >> 7;
    float acc[16];
#pragma unroll
    for (int i = 0; i < 16; i++) acc[i] = 0.f;
    for (int k = 0; k < FDIM; k++) {
        float wv = Wl[k * FDIM + c];
        const float* xp = &xs[(rg * 16) * FDIM + k];
#pragma unroll
        for (int i = 0; i < 16; i++) acc[i] += xp[i * FDIM] * wv;
    }
#pragma unroll
    for (int i = 0; i < 16; i++) {
        int r = row0 + rg * 16 + i;
        if (r < N) xw[(size_t)r * FDIM + c] = acc[i];
    }
}

// K2: per-node attention half-logits a_src[n,h], a_dst[n,h]
__global__ __launch_bounds__(256) void k_logits(const float* __restrict__ xw,
                                                const float* __restrict__ att,
                                                float* __restrict__ a_src,
                                                float* __restrict__ a_dst, int N)
{
    __shared__ float attl[HEADS * 2 * CD];
    int t = threadIdx.x;
    attl[t] = att[t];
    __syncthreads();
    int gid = blockIdx.x * 256 + t;
    if (gid >= N * HEADS) return;
    int n = gid >> 2, h = gid & 3;
    const float* xp = &xw[(size_t)n * FDIM + h * CD];
    const float* as = &attl[h * 2 * CD];
    const float* ad = as + CD;
    float s = 0.f, d = 0.f;
#pragma unroll
    for (int ci = 0; ci < CD; ci++) { float v = xp[ci]; s += v * as[ci]; d += v * ad[ci]; }
    a_src[gid] = s;
    a_dst[gid] = d;
}

// K3: zero accumulators via float4 (out_acc N*32, seg N*4)
__global__ void k_init(float4* __restrict__ out_acc, float4* __restrict__ seg, int N)
{
    int i = blockIdx.x * 256 + threadIdx.x;
    if (i < N * 8) out_acc[i] = make_float4(0.f, 0.f, 0.f, 0.f);
    if (i < N) seg[i] = make_float4(0.f, 0.f, 0.f, 0.f);
}

// K4: one thread per (edge,head); 4 adjacent lanes hit one 16B sector of seg
//     -> same-instruction atomic coalescing. Also stores exp to ealpha.
__global__ __launch_bounds__(256) void k_esum(const int* __restrict__ ei, int E,
                                              const float* __restrict__ a_src,
                                              const float* __restrict__ a_dst,
                                              float* __restrict__ seg,
                                              float* __restrict__ ealpha)
{
    int gid = blockIdx.x * 256 + threadIdx.x;
    if (gid >= E * HEADS) return;
    int e = gid >> 2, h = gid & 3;
    int r = ei[e], cl = ei[E + e];
    float a = a_src[r * 4 + h] + a_dst[cl * 4 + h];
    a = a >= 0.f ? a : 0.2f * a;
    float ex = __expf(a);
    ealpha[gid] = ex;
    atomicAdd(&seg[r * 4 + h], ex);
}

// K4b: inv_seg = 1/(seg+eps)
__global__ void k_inv(const float* __restrict__ seg, float* __restrict__ inv, int N)
{
    int i = blockIdx.x * 256 + threadIdx.x;
    if (i < N * HEADS) inv[i] = 1.f / (seg[i] + 1e-16f);
}

// K5: out_acc[col,c] += (1/H) * sum_h alpha[e,h]*xw[row,h,c]
// 32 lanes per edge (one per channel), 8 edges per block
__global__ __launch_bounds__(256) void k_scatter(const int* __restrict__ ei, int E,
                                                 const float* __restrict__ ealpha,
                                                 const float* __restrict__ inv,
                                                 const float* __restrict__ xw,
                                                 float* __restrict__ out_acc)
{
    int t = threadIdx.x;
    int le = t >> 5, c = t & 31;
    int e = blockIdx.x * 8 + le;
    if (e >= E) return;
    int r = ei[e], cl = ei[E + e];
    int lane = t & 63;
    float av = 0.f;
    if (c < 4) av = ealpha[e * 4 + c] * inv[r * 4 + c];
    float v = 0.f;
#pragma unroll
    for (int h = 0; h < 4; h++) {
        float ah = __shfl(av, (lane & 32) + h, 64);
        v += ah * xw[(size_t)r * FDIM + h * CD + c];
    }
    atomicAdd(&out_acc[cl * CD + c], 0.25f * v);
}

// K6: out = out_acc + bias  (float4)
__global__ void k_final(const float4* __restrict__ out_acc, const float4* __restrict__ bias,
                        float4* __restrict__ out, int N)
{
    int i = blockIdx.x * 256 + threadIdx.x;
    if (i >= N * 8) return;
    out[i] = make_float4(out_acc[i].x + bias[i & 7].x,
                         out_acc[i].y + bias[i & 7].y,
                         out_acc[i].z + bias[i & 7].z,
                         out_acc[i].w + bias[i & 7].w);
}

extern "C" void kernel_launch(void* const* d_in, const int* in_sizes, int n_in,
                              void* d_out, int out_size, void* d_ws, size_t ws_size,
                              hipStream_t stream)
{
    const float* x    = (const float*)d_in[0];
    const int*   ei   = (const int*)d_in[1];
    const float* w    = (const float*)d_in[2];
    const float* att  = (const float*)d_in[3];
    const float* bias = (const float*)d_in[4];
    float* out = (float*)d_out;
    int N = in_sizes[0] / FDIM;
    int E = in_sizes[1] / 2;

    float* ws      = (float*)d_ws;
    float* xw      = ws;                            // N*128
    float* a_src   = xw + (size_t)N * FDIM;         // N*4
    float* a_dst   = a_src + (size_t)N * HEADS;     // N*4
    float* seg     = a_dst + (size_t)N * HEADS;     // N*4
    float* inv     = seg + (size_t)N * HEADS;       // N*4
    float* out_acc = inv + (size_t)N * HEADS;       // N*32
    float* ealpha  = out_acc + (size_t)N * CD;      // E*4

    k_gemm<<<(N + 31) / 32, 256, 0, stream>>>(x, w, xw, N);
    k_logits<<<(N * HEADS + 255) / 256, 256, 0, stream>>>(xw, att, a_src, a_dst, N);
    k_init<<<(N * 8 + 255) / 256, 256, 0, stream>>>((float4*)out_acc, (float4*)seg, N);
    k_esum<<<(E * HEADS + 255) / 256, 256, 0, stream>>>(ei, E, a_src, a_dst, seg, ealpha);
    k_inv<<<(N * HEADS + 255) / 256, 256, 0, stream>>>(seg, inv, N);
    k_scatter<<<(E + 7) / 8, 256, 0, stream>>>(ei, E, ealpha, inv, xw, out_acc);
    k_final<<<(N * 8 + 255) / 256, 256, 0, stream>>>((float4*)out_acc, (const float4*)bias, (float4*)out, N);
}

// Round 4
// 279.901 us; speedup vs baseline: 1.4708x; 1.0305x over previous
//
#include <hip/hip_runtime.h>

#define FDIM 128
#define HEADS 4
#define CD 32
#define BM 64

static __device__ __forceinline__ unsigned short f2bf(float v) {
    unsigned u = __float_as_uint(v);
    u += 0x7FFF + ((u >> 16) & 1);          // round-nearest-even
    return (unsigned short)(u >> 16);
}
static __device__ __forceinline__ float bf2f(unsigned short u) {
    return __uint_as_float(((unsigned)u) << 16);
}

// K1: xwh[n][c][h] (bf16) = row-tile of x @ W.  VALU-bound tile:
// xs staged transposed [k][row] so inner loop is ds_read_b128 only.
__global__ __launch_bounds__(256) void k_gemm(const float* __restrict__ x,
                                              const float* __restrict__ w,
                                              unsigned short* __restrict__ xwh, int N)
{
    __shared__ float Wl[FDIM * FDIM];    // [k][c]   64 KB
    __shared__ float xs[FDIM * 68];      // [k][row] padded, 34.8 KB
    int t = threadIdx.x;
    int row0 = blockIdx.x * BM;
#pragma unroll
    for (int it = 0; it < 16; it++) {
        int i = t + 256 * it;
        ((float4*)Wl)[i] = ((const float4*)w)[i];
    }
#pragma unroll
    for (int it = 0; it < 8; it++) {
        int i = t + 256 * it;            // 0..2047
        int row = i >> 5, kq = i & 31;
        float4 v = make_float4(0.f, 0.f, 0.f, 0.f);
        if (row0 + row < N) v = ((const float4*)x)[(size_t)(row0 + row) * 32 + kq];
        xs[(kq * 4 + 0) * 68 + row] = v.x;
        xs[(kq * 4 + 1) * 68 + row] = v.y;
        xs[(kq * 4 + 2) * 68 + row] = v.z;
        xs[(kq * 4 + 3) * 68 + row] = v.w;
    }
    __syncthreads();
    int tx = t & 31, ty = t >> 5;
    int c0 = tx * 4, r0 = ty * 8;
    float acc[8][4];
#pragma unroll
    for (int i = 0; i < 8; i++)
#pragma unroll
        for (int j = 0; j < 4; j++) acc[i][j] = 0.f;
#pragma unroll 4
    for (int k = 0; k < FDIM; k++) {
        float4 wv = *(const float4*)&Wl[k * FDIM + c0];
        float4 xa = *(const float4*)&xs[k * 68 + r0];
        float4 xb = *(const float4*)&xs[k * 68 + r0 + 4];
        float xr[8] = {xa.x, xa.y, xa.z, xa.w, xb.x, xb.y, xb.z, xb.w};
        float wr[4] = {wv.x, wv.y, wv.z, wv.w};
#pragma unroll
        for (int i = 0; i < 8; i++)
#pragma unroll
            for (int j = 0; j < 4; j++) acc[i][j] += xr[i] * wr[j];
    }
    // epilogue: store bf16 head-interleaved  xwh[r*128 + ch*4 + h]
    int h = c0 >> 5, chb = c0 & 31;
#pragma unroll
    for (int i = 0; i < 8; i++) {
        int r = row0 + r0 + i;
        if (r < N) {
#pragma unroll
            for (int j = 0; j < 4; j++)
                xwh[(size_t)r * FDIM + (chb + j) * 4 + h] = f2bf(acc[i][j]);
        }
    }
}

// K2: per-node half-logits, one thread per node, all 4 heads
__global__ __launch_bounds__(256) void k_logits(const unsigned short* __restrict__ xwh,
                                                const float* __restrict__ att,
                                                float* __restrict__ a_src,
                                                float* __restrict__ a_dst, int N)
{
    __shared__ float attl[HEADS * 2 * CD];   // [h][2C]
    int t = threadIdx.x;
    attl[t] = att[t];
    __syncthreads();
    int n = blockIdx.x * 256 + t;
    if (n >= N) return;
    const ushort4* xp = (const ushort4*)(xwh + (size_t)n * FDIM);   // [c][h]
    float s[4] = {0.f, 0.f, 0.f, 0.f}, d[4] = {0.f, 0.f, 0.f, 0.f};
#pragma unroll 8
    for (int c = 0; c < CD; c++) {
        ushort4 p = xp[c];
        float f0 = bf2f(p.x), f1 = bf2f(p.y), f2 = bf2f(p.z), f3 = bf2f(p.w);
        s[0] += f0 * attl[0 * 64 + c];  d[0] += f0 * attl[0 * 64 + 32 + c];
        s[1] += f1 * attl[1 * 64 + c];  d[1] += f1 * attl[1 * 64 + 32 + c];
        s[2] += f2 * attl[2 * 64 + c];  d[2] += f2 * attl[2 * 64 + 32 + c];
        s[3] += f3 * attl[3 * 64 + c];  d[3] += f3 * attl[3 * 64 + 32 + c];
    }
    *(float4*)&a_src[n * 4] = make_float4(s[0], s[1], s[2], s[3]);
    *(float4*)&a_dst[n * 4] = make_float4(d[0], d[1], d[2], d[3]);
}

// K3: zero accumulators via float4 (out_acc N*32, seg N*4)
__global__ void k_init(float4* __restrict__ out_acc, float4* __restrict__ seg, int N)
{
    int i = blockIdx.x * 256 + threadIdx.x;
    if (i < N * 8) out_acc[i] = make_float4(0.f, 0.f, 0.f, 0.f);
    if (i < N) seg[i] = make_float4(0.f, 0.f, 0.f, 0.f);
}

// K4: one thread per (edge,head); 4 adjacent lanes hit one 16B sector of seg
__global__ __launch_bounds__(256) void k_esum(const int* __restrict__ ei, int E,
                                              const float* __restrict__ a_src,
                                              const float* __restrict__ a_dst,
                                              float* __restrict__ seg,
                                              float* __restrict__ ealpha)
{
    int gid = blockIdx.x * 256 + threadIdx.x;
    if (gid >= E * HEADS) return;
    int e = gid >> 2, h = gid & 3;
    int r = ei[e], cl = ei[E + e];
    float a = a_src[r * 4 + h] + a_dst[cl * 4 + h];
    a = a >= 0.f ? a : 0.2f * a;
    float ex = __expf(a);
    ealpha[gid] = ex;
    atomicAdd(&seg[r * 4 + h], ex);
}

// K4b: inv_seg = 1/(seg+eps)
__global__ void k_inv(const float* __restrict__ seg, float* __restrict__ inv, int N)
{
    int i = blockIdx.x * 256 + threadIdx.x;
    if (i < N * HEADS) inv[i] = 1.f / (seg[i] + 1e-16f);
}

// K5: out_acc[col,c] += (1/H) * sum_h alpha[e,h]*xwh[row,c,h]
// 32 lanes per edge; per-edge gather is ONE ushort4 load (256 B contiguous)
__global__ __launch_bounds__(256) void k_scatter(const int* __restrict__ ei, int E,
                                                 const float* __restrict__ ealpha,
                                                 const float* __restrict__ inv,
                                                 const unsigned short* __restrict__ xwh,
                                                 float* __restrict__ out_acc)
{
    int t = threadIdx.x;
    int le = t >> 5, c = t & 31;
    int e = blockIdx.x * 8 + le;
    if (e >= E) return;
    int r = ei[e], cl = ei[E + e];
    int lane = t & 63;
    float av = 0.f;
    if (c < 4) av = ealpha[e * 4 + c] * inv[r * 4 + c];
    ushort4 p = ((const ushort4*)xwh)[(size_t)r * 32 + c];
    float a0 = __shfl(av, (lane & 32) + 0, 64);
    float a1 = __shfl(av, (lane & 32) + 1, 64);
    float a2 = __shfl(av, (lane & 32) + 2, 64);
    float a3 = __shfl(av, (lane & 32) + 3, 64);
    float v = a0 * bf2f(p.x) + a1 * bf2f(p.y) + a2 * bf2f(p.z) + a3 * bf2f(p.w);
    atomicAdd(&out_acc[cl * CD + c], 0.25f * v);
}

// K6: out = out_acc + bias  (float4)
__global__ void k_final(const float4* __restrict__ out_acc, const float4* __restrict__ bias,
                        float4* __restrict__ out, int N)
{
    int i = blockIdx.x * 256 + threadIdx.x;
    if (i >= N * 8) return;
    float4 a = out_acc[i], b = bias[i & 7];
    out[i] = make_float4(a.x + b.x, a.y + b.y, a.z + b.z, a.w + b.w);
}

extern "C" void kernel_launch(void* const* d_in, const int* in_sizes, int n_in,
                              void* d_out, int out_size, void* d_ws, size_t ws_size,
                              hipStream_t stream)
{
    const float* x    = (const float*)d_in[0];
    const int*   ei   = (const int*)d_in[1];
    const float* w    = (const float*)d_in[2];
    const float* att  = (const float*)d_in[3];
    const float* bias = (const float*)d_in[4];
    float* out = (float*)d_out;
    int N = in_sizes[0] / FDIM;
    int E = in_sizes[1] / 2;

    unsigned short* xwh = (unsigned short*)d_ws;            // N*128 bf16 = 12.8 MB
    float* fws     = (float*)(xwh + (size_t)N * FDIM);
    float* a_src   = fws;                                   // N*4
    float* a_dst   = a_src + (size_t)N * HEADS;             // N*4
    float* seg     = a_dst + (size_t)N * HEADS;             // N*4
    float* inv     = seg + (size_t)N * HEADS;               // N*4
    float* out_acc = inv + (size_t)N * HEADS;               // N*32
    float* ealpha  = out_acc + (size_t)N * CD;              // E*4

    k_gemm<<<(N + BM - 1) / BM, 256, 0, stream>>>(x, w, xwh, N);
    k_logits<<<(N + 255) / 256, 256, 0, stream>>>(xwh, att, a_src, a_dst, N);
    k_init<<<(N * 8 + 255) / 256, 256, 0, stream>>>((float4*)out_acc, (float4*)seg, N);
    k_esum<<<(E * HEADS + 255) / 256, 256, 0, stream>>>(ei, E, a_src, a_dst, seg, ealpha);
    k_inv<<<(N * HEADS + 255) / 256, 256, 0, stream>>>(seg, inv, N);
    k_scatter<<<(E + 7) / 8, 256, 0, stream>>>(ei, E, ealpha, inv, xwh, out_acc);
    k_final<<<(N * 8 + 255) / 256, 256, 0, stream>>>((float4*)out_acc, (const float4*)bias, (float4*)out, N);
}

// Round 5
// 262.014 us; speedup vs baseline: 1.5712x; 1.0683x over previous
//
#include <hip/hip_runtime.h>

#define FDIM 128
#define HEADS 4
#define CD 32
#define BM 64
#define XPAD 68   // row stride for xs[k][row]; writes are lane-consecutive (conflict-free)

static __device__ __forceinline__ unsigned short f2bf(float v) {
    unsigned u = __float_as_uint(v);
    u += 0x7FFF + ((u >> 16) & 1);          // round-nearest-even
    return (unsigned short)(u >> 16);
}
static __device__ __forceinline__ float bf2f(unsigned short u) {
    return __uint_as_float(((unsigned)u) << 16);
}

// K1: xwh[n][c][h] (bf16) = row-tile of x @ W.
// Only the x-tile lives in LDS (35 KB -> 4 blocks/CU); W rows stream from
// global (L2-resident broadcast). xs staged [k][row] with row in the low
// lane bits: conflict-free ds_write, broadcast ds_read_b128 in the k-loop.
__global__ __launch_bounds__(256) void k_gemm(const float* __restrict__ x,
                                              const float* __restrict__ w,
                                              unsigned short* __restrict__ xwh, int N)
{
    __shared__ float xs[FDIM * XPAD];    // [k][row]  34.8 KB
    int t = threadIdx.x;
    int row0 = blockIdx.x * BM;
#pragma unroll
    for (int it = 0; it < 8; it++) {
        int i = t + 256 * it;            // 0..2047 = 64 rows x 32 float4
        int row = i & 63, kq = i >> 6;   // row varies with lane -> coalesced LDS writes
        float4 v = make_float4(0.f, 0.f, 0.f, 0.f);
        if (row0 + row < N) v = ((const float4*)x)[(size_t)(row0 + row) * 32 + kq];
        xs[(kq * 4 + 0) * XPAD + row] = v.x;
        xs[(kq * 4 + 1) * XPAD + row] = v.y;
        xs[(kq * 4 + 2) * XPAD + row] = v.z;
        xs[(kq * 4 + 3) * XPAD + row] = v.w;
    }
    __syncthreads();
    int tx = t & 31, ty = t >> 5;
    int c0 = tx * 4, r0 = ty * 8;
    const float4* w4 = (const float4*)w;
    float acc[8][4];
#pragma unroll
    for (int i = 0; i < 8; i++)
#pragma unroll
        for (int j = 0; j < 4; j++) acc[i][j] = 0.f;
#pragma unroll 4
    for (int k = 0; k < FDIM; k++) {
        float4 wv = w4[k * 32 + tx];                      // global, L2 broadcast
        float4 xa = *(const float4*)&xs[k * XPAD + r0];   // broadcast within ty group
        float4 xb = *(const float4*)&xs[k * XPAD + r0 + 4];
        float xr[8] = {xa.x, xa.y, xa.z, xa.w, xb.x, xb.y, xb.z, xb.w};
        float wr[4] = {wv.x, wv.y, wv.z, wv.w};
#pragma unroll
        for (int i = 0; i < 8; i++)
#pragma unroll
            for (int j = 0; j < 4; j++) acc[i][j] += xr[i] * wr[j];
    }
    // epilogue: store bf16 head-interleaved  xwh[r*128 + ch*4 + h]
    int h = c0 >> 5, chb = c0 & 31;
#pragma unroll
    for (int i = 0; i < 8; i++) {
        int r = row0 + r0 + i;
        if (r < N) {
#pragma unroll
            for (int j = 0; j < 4; j++)
                xwh[(size_t)r * FDIM + (chb + j) * 4 + h] = f2bf(acc[i][j]);
        }
    }
}

// K2: per-node half-logits, one thread per node, all 4 heads
__global__ __launch_bounds__(256) void k_logits(const unsigned short* __restrict__ xwh,
                                                const float* __restrict__ att,
                                                float* __restrict__ a_src,
                                                float* __restrict__ a_dst, int N)
{
    __shared__ float attl[HEADS * 2 * CD];   // [h][2C]
    int t = threadIdx.x;
    attl[t] = att[t];
    __syncthreads();
    int n = blockIdx.x * 256 + t;
    if (n >= N) return;
    const ushort4* xp = (const ushort4*)(xwh + (size_t)n * FDIM);   // [c][h]
    float s[4] = {0.f, 0.f, 0.f, 0.f}, d[4] = {0.f, 0.f, 0.f, 0.f};
#pragma unroll 8
    for (int c = 0; c < CD; c++) {
        ushort4 p = xp[c];
        float f0 = bf2f(p.x), f1 = bf2f(p.y), f2 = bf2f(p.z), f3 = bf2f(p.w);
        s[0] += f0 * attl[0 * 64 + c];  d[0] += f0 * attl[0 * 64 + 32 + c];
        s[1] += f1 * attl[1 * 64 + c];  d[1] += f1 * attl[1 * 64 + 32 + c];
        s[2] += f2 * attl[2 * 64 + c];  d[2] += f2 * attl[2 * 64 + 32 + c];
        s[3] += f3 * attl[3 * 64 + c];  d[3] += f3 * attl[3 * 64 + 32 + c];
    }
    *(float4*)&a_src[n * 4] = make_float4(s[0], s[1], s[2], s[3]);
    *(float4*)&a_dst[n * 4] = make_float4(d[0], d[1], d[2], d[3]);
}

// K3: zero accumulators via float4 (out_acc N*32, seg N*4)
__global__ void k_init(float4* __restrict__ out_acc, float4* __restrict__ seg, int N)
{
    int i = blockIdx.x * 256 + threadIdx.x;
    if (i < N * 8) out_acc[i] = make_float4(0.f, 0.f, 0.f, 0.f);
    if (i < N) seg[i] = make_float4(0.f, 0.f, 0.f, 0.f);
}

// K4: one thread per (edge,head); 4 adjacent lanes hit one 16B sector of seg
__global__ __launch_bounds__(256) void k_esum(const int* __restrict__ ei, int E,
                                              const float* __restrict__ a_src,
                                              const float* __restrict__ a_dst,
                                              float* __restrict__ seg,
                                              float* __restrict__ ealpha)
{
    int gid = blockIdx.x * 256 + threadIdx.x;
    if (gid >= E * HEADS) return;
    int e = gid >> 2, h = gid & 3;
    int r = ei[e], cl = ei[E + e];
    float a = a_src[r * 4 + h] + a_dst[cl * 4 + h];
    a = a >= 0.f ? a : 0.2f * a;
    float ex = __expf(a);
    ealpha[gid] = ex;
    atomicAdd(&seg[r * 4 + h], ex);
}

// K5: out_acc[col,c] += (1/H) * sum_h alpha[e,h]*xwh[row,c,h]
// 32 lanes per edge; per-edge gather is ONE ushort4 load (256 B contiguous).
// inv folded in: 4 lanes read seg and rcp.
__global__ __launch_bounds__(256) void k_scatter(const int* __restrict__ ei, int E,
                                                 const float* __restrict__ ealpha,
                                                 const float* __restrict__ seg,
                                                 const unsigned short* __restrict__ xwh,
                                                 float* __restrict__ out_acc)
{
    int t = threadIdx.x;
    int le = t >> 5, c = t & 31;
    int e = blockIdx.x * 8 + le;
    if (e >= E) return;
    int r = ei[e], cl = ei[E + e];
    int lane = t & 63;
    float av = 0.f;
    if (c < 4) av = ealpha[e * 4 + c] / (seg[r * 4 + c] + 1e-16f);
    ushort4 p = ((const ushort4*)xwh)[(size_t)r * 32 + c];
    float a0 = __shfl(av, (lane & 32) + 0, 64);
    float a1 = __shfl(av, (lane & 32) + 1, 64);
    float a2 = __shfl(av, (lane & 32) + 2, 64);
    float a3 = __shfl(av, (lane & 32) + 3, 64);
    float v = a0 * bf2f(p.x) + a1 * bf2f(p.y) + a2 * bf2f(p.z) + a3 * bf2f(p.w);
    atomicAdd(&out_acc[cl * CD + c], 0.25f * v);
}

// K6: out = out_acc + bias  (float4)
__global__ void k_final(const float4* __restrict__ out_acc, const float4* __restrict__ bias,
                        float4* __restrict__ out, int N)
{
    int i = blockIdx.x * 256 + threadIdx.x;
    if (i >= N * 8) return;
    float4 a = out_acc[i], b = bias[i & 7];
    out[i] = make_float4(a.x + b.x, a.y + b.y, a.z + b.z, a.w + b.w);
}

extern "C" void kernel_launch(void* const* d_in, const int* in_sizes, int n_in,
                              void* d_out, int out_size, void* d_ws, size_t ws_size,
                              hipStream_t stream)
{
    const float* x    = (const float*)d_in[0];
    const int*   ei   = (const int*)d_in[1];
    const float* w    = (const float*)d_in[2];
    const float* att  = (const float*)d_in[3];
    const float* bias = (const float*)d_in[4];
    float* out = (float*)d_out;
    int N = in_sizes[0] / FDIM;
    int E = in_sizes[1] / 2;

    unsigned short* xwh = (unsigned short*)d_ws;            // N*128 bf16
    float* fws     = (float*)(xwh + (size_t)N * FDIM);
    float* a_src   = fws;                                   // N*4
    float* a_dst   = a_src + (size_t)N * HEADS;             // N*4
    float* seg     = a_dst + (size_t)N * HEADS;             // N*4
    float* out_acc = seg + (size_t)N * HEADS;               // N*32
    float* ealpha  = out_acc + (size_t)N * CD;              // E*4

    k_gemm<<<(N + BM - 1) / BM, 256, 0, stream>>>(x, w, xwh, N);
    k_logits<<<(N + 255) / 256, 256, 0, stream>>>(xwh, att, a_src, a_dst, N);
    k_init<<<(N * 8 + 255) / 256, 256, 0, stream>>>((float4*)out_acc, (float4*)seg, N);
    k_esum<<<(E * HEADS + 255) / 256, 256, 0, stream>>>(ei, E, a_src, a_dst, seg, ealpha);
    k_scatter<<<(E + 7) / 8, 256, 0, stream>>>(ei, E, ealpha, seg, xwh, out_acc);
    k_final<<<(N * 8 + 255) / 256, 256, 0, stream>>>((float4*)out_acc, (const float4*)bias, (float4*)out, N);
}